// Round 1
// baseline (181.902 us; speedup 1.0000x reference)
//
#include <hip/hip_runtime.h>
#include <cstdint>
#include <cstddef>

// Problem constants (F, H, D, A, B) = (500, 2000, 64, 64, 4096)
#define F_N 500
#define H_N 2000
#define JN  2500   // F + H
#define D_N 64
#define A_N 64
#define B_N 4096
#define NB_FUSED 256   // fused-kernel grid: must stay <= 256 for co-residency proof

// ---------------------------------------------------------------------------
// Kernel 1: pre_f[i][a] = feat[i,:] @ W1[:,a] + bw[a]   (row-major, 500x64)
//           pre_w[j][a] = full[j,:] @ W2[:,a]           (row-major, 2500x64)
// One wave per row; lane = a. Also zeroes the grid-barrier words for k_fused
// (workspace is poisoned by the harness, so in-stream zeroing is mandatory).
// ---------------------------------------------------------------------------
__global__ __launch_bounds__(256) void k_pre(
    const float* __restrict__ feat, const float* __restrict__ hid,
    const float* __restrict__ Ww,   const float* __restrict__ bw,
    float* __restrict__ pre_f, float* __restrict__ pre_w,
    int* __restrict__ barrier_ws)
{
    if (blockIdx.x == 0 && threadIdx.x < 2) barrier_ws[threadIdx.x] = 0;

    const int lane = threadIdx.x & 63;
    const int wave = threadIdx.x >> 6;
    int row = blockIdx.x * 4 + wave;                   // 0..2999
    row = __builtin_amdgcn_readfirstlane(row);         // force scalar
    if (row >= F_N + JN) return;

    const float* emb;
    const float* W;
    float*       outp;
    float acc0, acc1 = 0.0f;

    if (row < F_N) {                 // pre_f row (bias folded in)
        emb  = feat + (size_t)row * D_N;
        W    = Ww;                   // W1 = Ww[0:64]
        outp = pre_f + (size_t)row * A_N;
        acc0 = bw[lane];
    } else {                         // pre_w row
        const int j = row - F_N;
        emb  = (j < F_N) ? (feat + (size_t)j * D_N)
                         : (hid + (size_t)(j - F_N) * D_N);
        W    = Ww + D_N * A_N;       // W2 = Ww[64:128]
        outp = pre_w + (size_t)j * A_N;
        acc0 = 0.0f;
    }

    #pragma unroll
    for (int d = 0; d < D_N; d += 2) {
        acc0 = fmaf(emb[d],     W[(d    ) * A_N + lane], acc0);  // emb: s_load
        acc1 = fmaf(emb[d + 1], W[(d + 1) * A_N + lane], acc1);
    }
    outp[lane] = acc0 + acc1;        // coalesced row-major store
}

// ---------------------------------------------------------------------------
// Device-scope grid barrier (counter + generation). Safe because:
//  - grid = 256 blocks <= 256 CUs, 53 KB LDS < 64 KB, modest VGPR -> every
//    block is resident simultaneously (capacity >= 2 blocks/CU).
//  - AGENT-scope atomics are coherent across the 8 non-coherent XCD L2s.
//  - __threadfence() (release) before arrive makes ctx writes visible;
//    ACQUIRE poll/fetch_add invalidates stale L1/L2 lines on exit.
// ---------------------------------------------------------------------------
__device__ __forceinline__ void grid_barrier(int* __restrict__ ctr,
                                             int* __restrict__ gen,
                                             int nblocks)
{
    __syncthreads();
    if (threadIdx.x == 0) {
        __threadfence();   // release ctx stores to device scope
        const int g = __hip_atomic_load(gen, __ATOMIC_RELAXED,
                                        __HIP_MEMORY_SCOPE_AGENT);
        const int old = __hip_atomic_fetch_add(ctr, 1, __ATOMIC_ACQ_REL,
                                               __HIP_MEMORY_SCOPE_AGENT);
        if (old == nblocks - 1) {
            __hip_atomic_store(gen, g + 1, __ATOMIC_RELEASE,
                               __HIP_MEMORY_SCOPE_AGENT);
        } else {
            while (__hip_atomic_load(gen, __ATOMIC_ACQUIRE,
                                     __HIP_MEMORY_SCOPE_AGENT) == g) {
                __builtin_amdgcn_s_sleep(2);
            }
        }
    }
    __syncthreads();
}

// ---------------------------------------------------------------------------
// Fused kernel: attention (500 i's, 2 per block for blocks 0..249)
//               -> grid barrier -> out = values @ ctx (16 rows per block).
// Removes one full dispatch boundary (the dominant cost per the R0 theory).
// ---------------------------------------------------------------------------
__global__ __launch_bounds__(256) void k_fused(
    const float* __restrict__ feat, const float* __restrict__ hid,
    const float* __restrict__ pre_f, const float* __restrict__ pre_w,
    const float* __restrict__ Wu,   const void* __restrict__ mask,
    const float* __restrict__ values,
    float* __restrict__ ctx, float* __restrict__ out,
    int* __restrict__ barrier_ws)
{
    const int tid  = threadIdx.x;
    const int lane = tid & 63;
    const int wave = tid >> 6;

    // ---- attn-phase LDS ----
    __shared__ int   list[JN];
    __shared__ float earr[JN];
    __shared__ float s_ctx[4][64];
    __shared__ int   nact;
    // ---- out-phase LDS ----
    __shared__ float ctx_l[100 * 64];            // 25.6 KB
    __shared__ float vals_l[16 * 100];           // 6.4 KB

    // =======================================================================
    // Phase 1: attention. Blocks 0..249 handle i = 2b and 2b+1.
    // =======================================================================
    if (blockIdx.x < 250) {
        // runtime mask-dtype detection: bool bytes vs int32
        const uint32_t* mw = (const uint32_t*)mask;
        const uint32_t probe = mw[lane] | mw[64 + lane] | mw[128 + lane] | mw[192 + lane];
        const bool byteMode = (__ballot(probe > 1u) != 0ull);

        for (int rep = 0; rep < 2; ++rep) {
            const int i = blockIdx.x * 2 + rep;

            if (tid == 0) nact = 0;
            __syncthreads();

            const uint8_t*  mb = (const uint8_t*)mask + (size_t)i * JN;
            const uint32_t* mi = (const uint32_t*)mask + (size_t)i * JN;

            // --- A: compaction ------------------------------------------------
            for (int t = tid; t < 2560; t += 256) {        // 10 uniform passes
                uint32_t m = 0;
                if (t < JN) m = byteMode ? (uint32_t)mb[t] : mi[t];
                const unsigned long long act = __ballot(m != 0);
                const int cnt = __popcll(act);
                int base = 0;
                if (lane == 0 && cnt) base = atomicAdd(&nact, cnt);
                base = __shfl(base, 0, 64);
                if (m) {
                    const int rank = __popcll(act & ((1ull << lane) - 1ull));
                    list[base + rank] = t;
                }
            }
            __syncthreads();
            const int n = nact;

            // --- B: per-thread score for one active j (row-major, L2-resident)
            const float* pf = pre_f + (size_t)i * A_N;     // block-uniform s_loads
            for (int idx = tid; idx < n; idx += 256) {
                const int j = list[idx];
                const float4* pwj = (const float4*)(pre_w + (size_t)j * A_N);
                float s = 0.0f;
                #pragma unroll
                for (int q = 0; q < 16; ++q) {
                    const float4 v = pwj[q];
                    const int a = q * 4;
                    // tanh(x) = 1 - 2/(exp(2x)+1); v_rcp_f32 instead of precise div
                    const float x0 = pf[a + 0] + v.x;
                    const float x1 = pf[a + 1] + v.y;
                    const float x2 = pf[a + 2] + v.z;
                    const float x3 = pf[a + 3] + v.w;
                    const float t0 = fmaf(-2.0f, __builtin_amdgcn_rcpf(__expf(2.0f * x0) + 1.0f), 1.0f);
                    const float t1 = fmaf(-2.0f, __builtin_amdgcn_rcpf(__expf(2.0f * x1) + 1.0f), 1.0f);
                    const float t2 = fmaf(-2.0f, __builtin_amdgcn_rcpf(__expf(2.0f * x2) + 1.0f), 1.0f);
                    const float t3 = fmaf(-2.0f, __builtin_amdgcn_rcpf(__expf(2.0f * x3) + 1.0f), 1.0f);
                    s = fmaf(Wu[a + 0], t0, s);
                    s = fmaf(Wu[a + 1], t1, s);
                    s = fmaf(Wu[a + 2], t2, s);
                    s = fmaf(Wu[a + 3], t3, s);
                }
                earr[idx] = __expf(s);
            }
            __syncthreads();

            // --- C: context accumulation (lane = d), 4x unrolled --------------
            float cacc = 0.0f;
            int idx = wave;                                // stride 4 per wave
            for (; idx + 12 < n; idx += 16) {
                const float e0 = earr[idx];      const int j0 = list[idx];
                const float e1 = earr[idx + 4];  const int j1 = list[idx + 4];
                const float e2 = earr[idx + 8];  const int j2 = list[idx + 8];
                const float e3 = earr[idx + 12]; const int j3 = list[idx + 12];
                const float* r0 = (j0 < F_N) ? (feat + (size_t)j0 * D_N) : (hid + (size_t)(j0 - F_N) * D_N);
                const float* r1 = (j1 < F_N) ? (feat + (size_t)j1 * D_N) : (hid + (size_t)(j1 - F_N) * D_N);
                const float* r2 = (j2 < F_N) ? (feat + (size_t)j2 * D_N) : (hid + (size_t)(j2 - F_N) * D_N);
                const float* r3 = (j3 < F_N) ? (feat + (size_t)j3 * D_N) : (hid + (size_t)(j3 - F_N) * D_N);
                const float v0 = r0[lane];
                const float v1 = r1[lane];
                const float v2 = r2[lane];
                const float v3 = r3[lane];
                cacc = fmaf(e0, v0, cacc);
                cacc = fmaf(e1, v1, cacc);
                cacc = fmaf(e2, v2, cacc);
                cacc = fmaf(e3, v3, cacc);
            }
            for (; idx < n; idx += 4) {
                const float e = earr[idx];
                const int   j = list[idx];
                const float* row = (j < F_N) ? (feat + (size_t)j * D_N)
                                             : (hid + (size_t)(j - F_N) * D_N);
                cacc = fmaf(e, row[lane], cacc);
            }
            s_ctx[wave][lane] = cacc;
            __syncthreads();

            if (wave == 0) {
                const float c4 = s_ctx[0][lane] + s_ctx[1][lane] + s_ctx[2][lane] + s_ctx[3][lane];
                float ss = 0.0f;
                for (int k = lane; k < n; k += 64) ss += earr[k];
                #pragma unroll
                for (int off = 1; off < 64; off <<= 1) ss += __shfl_xor(ss, off, 64);
                if (ss == 0.0f) ss = 1.0f;                 // reference semantics
                ctx[(size_t)i * D_N + lane] = c4 / ss;
            }
            // rep-loop WAR safety: next rep's first __syncthreads (after nact
            // reset) orders wave0's earr reads before rep2's earr writes.
        }
    }

    // =======================================================================
    // Grid barrier: all 256 blocks' ctx writes visible before out phase.
    // =======================================================================
    grid_barrier(barrier_ws + 0, barrier_ws + 1, NB_FUSED);

    // =======================================================================
    // Phase 2: out = values (4096x500) @ ctx (500x64). 16 rows/block,
    // K in 5 chunks of 100, register-prefetched LDS staging (R4 design).
    // =======================================================================
    {
        const int rowB = blockIdx.x * 16;            // block's first row
        const int r0   = wave * 4;                   // wave's rows within block

        float4 cbuf[7];                              // ctx chunk: 1600 float4 / 256 thr
        float4 vbuf[2];                              // vals chunk: 400 float4 / 256 thr

        float acc0 = 0.0f, acc1 = 0.0f, acc2 = 0.0f, acc3 = 0.0f;

        // ---- prefetch chunk 0 into registers (lane-coalesced) ----
        {
            const float4* cp = (const float4*)(ctx);           // k0 = 0
            #pragma unroll
            for (int q = 0; q < 7; ++q) {
                const int t = tid + q * 256;
                if (t < 1600) cbuf[q] = cp[t];
            }
            #pragma unroll
            for (int q = 0; q < 2; ++q) {
                const int t = tid + q * 256;
                if (t < 400) {
                    const int r = t / 25, c = t % 25;
                    vbuf[q] = *(const float4*)(values + (size_t)(rowB + r) * 500 + c * 4);
                }
            }
        }

        for (int chunk = 0; chunk < 5; ++chunk) {
            __syncthreads();                         // LDS free (prev compute done)
            // ---- registers -> LDS (waits on the prefetch loads) ----
            {
                float4* cl = (float4*)ctx_l;
                #pragma unroll
                for (int q = 0; q < 7; ++q) {
                    const int t = tid + q * 256;
                    if (t < 1600) cl[t] = cbuf[q];
                }
                float4* vl = (float4*)vals_l;
                #pragma unroll
                for (int q = 0; q < 2; ++q) {
                    const int t = tid + q * 256;
                    if (t < 400) vl[t] = vbuf[q];
                }
            }
            __syncthreads();

            // ---- issue prefetch of chunk+1 (loads fly during compute) ----
            if (chunk < 4) {
                const int k0 = (chunk + 1) * 100;
                const float4* cp = (const float4*)(ctx + (size_t)k0 * 64);
                #pragma unroll
                for (int q = 0; q < 7; ++q) {
                    const int t = tid + q * 256;
                    if (t < 1600) cbuf[q] = cp[t];
                }
                #pragma unroll
                for (int q = 0; q < 2; ++q) {
                    const int t = tid + q * 256;
                    if (t < 400) {
                        const int r = t / 25, c = t % 25;
                        vbuf[q] = *(const float4*)(values + (size_t)(rowB + r) * 500 + k0 + c * 4);
                    }
                }
            }

            // ---- compute current chunk from LDS ----
            const float* v0 = vals_l + (r0 + 0) * 100;
            const float* v1 = vals_l + (r0 + 1) * 100;
            const float* v2 = vals_l + (r0 + 2) * 100;
            const float* v3 = vals_l + (r0 + 3) * 100;
            #pragma unroll 5
            for (int k = 0; k < 100; k += 4) {
                const float4 a = *(const float4*)(v0 + k);   // uniform b128 broadcast
                const float4 b = *(const float4*)(v1 + k);
                const float4 c = *(const float4*)(v2 + k);
                const float4 d = *(const float4*)(v3 + k);
                const float c0 = ctx_l[(k + 0) * 64 + lane];
                const float c1 = ctx_l[(k + 1) * 64 + lane];
                const float c2 = ctx_l[(k + 2) * 64 + lane];
                const float c3 = ctx_l[(k + 3) * 64 + lane];
                acc0 = fmaf(a.x, c0, acc0); acc0 = fmaf(a.y, c1, acc0);
                acc0 = fmaf(a.z, c2, acc0); acc0 = fmaf(a.w, c3, acc0);
                acc1 = fmaf(b.x, c0, acc1); acc1 = fmaf(b.y, c1, acc1);
                acc1 = fmaf(b.z, c2, acc1); acc1 = fmaf(b.w, c3, acc1);
                acc2 = fmaf(c.x, c0, acc2); acc2 = fmaf(c.y, c1, acc2);
                acc2 = fmaf(c.z, c2, acc2); acc2 = fmaf(c.w, c3, acc2);
                acc3 = fmaf(d.x, c0, acc3); acc3 = fmaf(d.y, c1, acc3);
                acc3 = fmaf(d.z, c2, acc3); acc3 = fmaf(d.w, c3, acc3);
            }
        }

        const int gr = rowB + r0;
        out[(size_t)(gr + 0) * 64 + lane] = acc0;    // coalesced 256 B per wave
        out[(size_t)(gr + 1) * 64 + lane] = acc1;
        out[(size_t)(gr + 2) * 64 + lane] = acc2;
        out[(size_t)(gr + 3) * 64 + lane] = acc3;
    }
}

// ---------------------------------------------------------------------------
extern "C" void kernel_launch(void* const* d_in, const int* in_sizes, int n_in,
                              void* d_out, int out_size, void* d_ws, size_t ws_size,
                              hipStream_t stream)
{
    const float* values = (const float*)d_in[0];   // (4096, 500)
    const float* feat   = (const float*)d_in[1];   // (500, 64)
    const float* hid    = (const float*)d_in[2];   // (2000, 64)
    const float* Ww     = (const float*)d_in[3];   // (128, 64)
    const float* bw     = (const float*)d_in[4];   // (64,)
    const float* Wu     = (const float*)d_in[5];   // (64, 1)
    const void*  mask   = d_in[6];                 // (500, 2500, 1) — dtype detected on device
    float* out = (float*)d_out;                    // (4096, 64)

    // Workspace layout (floats):
    //   pre_f[500*64] | pre_w[2500*64] | ctx[500*64] | barrier{ctr,gen}
    float* wsf   = (float*)d_ws;
    float* pre_f = wsf;                  // 32000 floats
    float* pre_w = wsf + 32000;          // 160000 floats (row-major 2500 x 64)
    float* ctx   = wsf + 192000;         // 32000 floats
    int*   bar   = (int*)(wsf + 224000); // 2 ints, 64B-aligned, zeroed by k_pre

    k_pre  <<<750, 256, 0, stream>>>(feat, hid, Ww, bw, pre_f, pre_w, bar);
    k_fused<<<NB_FUSED, 256, 0, stream>>>(feat, hid, pre_f, pre_w, Wu, mask,
                                          values, ctx, out, bar);
}

// Round 2
// 108.813 us; speedup vs baseline: 1.6717x; 1.6717x over previous
//
#include <hip/hip_runtime.h>
#include <cstdint>
#include <cstddef>

// Problem constants (F, H, D, A, B) = (500, 2000, 64, 64, 4096)
#define F_N 500
#define H_N 2000
#define JN  2500   // F + H
#define D_N 64
#define A_N 64
#define B_N 4096

#define SPLIT  2         // blocks per attention row i
#define JCHUNK 1250      // JN / SPLIT

// ---------------------------------------------------------------------------
// Kernel 1: pre_f[i][a] = feat[i,:] @ W1[:,a] + bw[a]   (row-major, 500x64)
//           pre_w[j][a] = full[j,:] @ W2[:,a]           (row-major, 2500x64)
// One wave per row; lane = a. Also zeroes csum/esum (32512 floats) for the
// atomic partial-sum accumulation in k_attn (workspace is poisoned).
// ---------------------------------------------------------------------------
__global__ __launch_bounds__(256) void k_pre(
    const float* __restrict__ feat, const float* __restrict__ hid,
    const float* __restrict__ Ww,   const float* __restrict__ bw,
    float* __restrict__ pre_f, float* __restrict__ pre_w,
    float* __restrict__ zero_region)   // csum[32000] | esum[512], contiguous
{
    const int gt = blockIdx.x * 256 + threadIdx.x;
    if (gt < 32512) zero_region[gt] = 0.0f;

    const int lane = threadIdx.x & 63;
    const int wave = threadIdx.x >> 6;
    int row = blockIdx.x * 4 + wave;                   // 0..2999
    row = __builtin_amdgcn_readfirstlane(row);         // force scalar
    if (row >= F_N + JN) return;

    const float* emb;
    const float* W;
    float*       outp;
    float acc0, acc1 = 0.0f;

    if (row < F_N) {                 // pre_f row (bias folded in)
        emb  = feat + (size_t)row * D_N;
        W    = Ww;                   // W1 = Ww[0:64]
        outp = pre_f + (size_t)row * A_N;
        acc0 = bw[lane];
    } else {                         // pre_w row
        const int j = row - F_N;
        emb  = (j < F_N) ? (feat + (size_t)j * D_N)
                         : (hid + (size_t)(j - F_N) * D_N);
        W    = Ww + D_N * A_N;       // W2 = Ww[64:128]
        outp = pre_w + (size_t)j * A_N;
        acc0 = 0.0f;
    }

    #pragma unroll
    for (int d = 0; d < D_N; d += 2) {
        acc0 = fmaf(emb[d],     W[(d    ) * A_N + lane], acc0);  // emb: s_load
        acc1 = fmaf(emb[d + 1], W[(d + 1) * A_N + lane], acc1);
    }
    outp[lane] = acc0 + acc1;        // coalesced row-major store
}

// ---------------------------------------------------------------------------
// Kernel 2: attention partials. Grid = 1000 blocks: block b handles
// i = b/2, j-range [ (b&1)*1250, (b&1)*1250+1250 ).
// Phases: compaction (ballot) -> per-thread score (tanh MLP) -> partial
// context sum. Partials accumulate into global csum[i][d] / esum[i] via
// float atomicAdd (device scope). Normalization happens in k_out.
// ~4 blocks/CU resident (16 waves/CU) -> 4x the latency hiding of R1.
// ---------------------------------------------------------------------------
__global__ __launch_bounds__(256) void k_attn(
    const float* __restrict__ feat, const float* __restrict__ hid,
    const float* __restrict__ pre_f, const float* __restrict__ pre_w,
    const float* __restrict__ Wu,   const void* __restrict__ mask,
    float* __restrict__ csum, float* __restrict__ esum)
{
    const int tid  = threadIdx.x;
    const int lane = tid & 63;
    const int wave = tid >> 6;
    const int i    = blockIdx.x >> 1;          // 0..499
    const int sub  = blockIdx.x & 1;           // 0..1
    const int jbase = sub * JCHUNK;

    __shared__ int   list[JCHUNK];
    __shared__ float earr[JCHUNK];
    __shared__ float s_ctx[4][64];
    __shared__ int   nact;

    if (tid == 0) nact = 0;
    __syncthreads();

    // --- runtime mask-dtype detection: bool bytes vs int32 -----------------
    const uint32_t* mw = (const uint32_t*)mask;
    const uint32_t probe = mw[lane] | mw[64 + lane] | mw[128 + lane] | mw[192 + lane];
    const bool byteMode = (__ballot(probe > 1u) != 0ull);

    const uint8_t*  mb = (const uint8_t*)mask + (size_t)i * JN + jbase;
    const uint32_t* mi = (const uint32_t*)mask + (size_t)i * JN + jbase;

    // --- A: compaction over this block's 1250 j's (5 uniform passes) --------
    for (int t = tid; t < 1280; t += 256) {
        uint32_t m = 0;
        if (t < JCHUNK) m = byteMode ? (uint32_t)mb[t] : mi[t];
        const unsigned long long act = __ballot(m != 0);
        const int cnt = __popcll(act);
        int base = 0;
        if (lane == 0 && cnt) base = atomicAdd(&nact, cnt);
        base = __shfl(base, 0, 64);
        if (m) {
            const int rank = __popcll(act & ((1ull << lane) - 1ull));
            list[base + rank] = jbase + t;     // store GLOBAL j
        }
    }
    __syncthreads();
    const int n = nact;                        // ~125 active

    // --- B: per-thread score for one active j (pre_w rows L2-resident) -----
    const float* pf = pre_f + (size_t)i * A_N; // block-uniform -> s_loads
    for (int idx = tid; idx < n; idx += 256) {
        const int j = list[idx];
        const float4* pwj = (const float4*)(pre_w + (size_t)j * A_N); // 256B-aligned
        float s = 0.0f;
        #pragma unroll
        for (int q = 0; q < 16; ++q) {
            const float4 v = pwj[q];
            const int a = q * 4;
            // tanh(x) = 1 - 2/(exp(2x)+1); v_rcp_f32 is plenty accurate here
            const float x0 = pf[a + 0] + v.x;
            const float x1 = pf[a + 1] + v.y;
            const float x2 = pf[a + 2] + v.z;
            const float x3 = pf[a + 3] + v.w;
            const float t0 = fmaf(-2.0f, __builtin_amdgcn_rcpf(__expf(2.0f * x0) + 1.0f), 1.0f);
            const float t1 = fmaf(-2.0f, __builtin_amdgcn_rcpf(__expf(2.0f * x1) + 1.0f), 1.0f);
            const float t2 = fmaf(-2.0f, __builtin_amdgcn_rcpf(__expf(2.0f * x2) + 1.0f), 1.0f);
            const float t3 = fmaf(-2.0f, __builtin_amdgcn_rcpf(__expf(2.0f * x3) + 1.0f), 1.0f);
            s = fmaf(Wu[a + 0], t0, s);
            s = fmaf(Wu[a + 1], t1, s);
            s = fmaf(Wu[a + 2], t2, s);
            s = fmaf(Wu[a + 3], t3, s);
        }
        earr[idx] = __expf(s);
    }
    __syncthreads();

    // --- C: partial context accumulation (lane = d), 4x unrolled ------------
    float cacc = 0.0f;
    int idx = wave;                                    // stride 4 per wave
    for (; idx + 12 < n; idx += 16) {
        const float e0 = earr[idx];      const int j0 = list[idx];
        const float e1 = earr[idx + 4];  const int j1 = list[idx + 4];
        const float e2 = earr[idx + 8];  const int j2 = list[idx + 8];
        const float e3 = earr[idx + 12]; const int j3 = list[idx + 12];
        const float* r0 = (j0 < F_N) ? (feat + (size_t)j0 * D_N) : (hid + (size_t)(j0 - F_N) * D_N);
        const float* r1 = (j1 < F_N) ? (feat + (size_t)j1 * D_N) : (hid + (size_t)(j1 - F_N) * D_N);
        const float* r2 = (j2 < F_N) ? (feat + (size_t)j2 * D_N) : (hid + (size_t)(j2 - F_N) * D_N);
        const float* r3 = (j3 < F_N) ? (feat + (size_t)j3 * D_N) : (hid + (size_t)(j3 - F_N) * D_N);
        const float v0 = r0[lane];
        const float v1 = r1[lane];
        const float v2 = r2[lane];
        const float v3 = r3[lane];
        cacc = fmaf(e0, v0, cacc);
        cacc = fmaf(e1, v1, cacc);
        cacc = fmaf(e2, v2, cacc);
        cacc = fmaf(e3, v3, cacc);
    }
    for (; idx < n; idx += 4) {
        const float e = earr[idx];
        const int   j = list[idx];
        const float* row = (j < F_N) ? (feat + (size_t)j * D_N)
                                     : (hid + (size_t)(j - F_N) * D_N);
        cacc = fmaf(e, row[lane], cacc);
    }
    s_ctx[wave][lane] = cacc;
    __syncthreads();

    if (wave == 0) {
        const float c4 = s_ctx[0][lane] + s_ctx[1][lane] + s_ctx[2][lane] + s_ctx[3][lane];
        float ss = 0.0f;
        for (int k = lane; k < n; k += 64) ss += earr[k];
        #pragma unroll
        for (int off = 1; off < 64; off <<= 1) ss += __shfl_xor(ss, off, 64);
        atomicAdd(&csum[(size_t)i * D_N + lane], c4);   // 64 lanes, distinct addrs
        if (lane == 0) atomicAdd(&esum[i], ss);
    }
}

// ---------------------------------------------------------------------------
// Kernel 3: out = values (4096x500) @ (csum/esum) (500x64).
// 512 blocks x 256 thr, 8 rows/block (2 rows/wave), 2 blocks/CU.
// ctx chunk (100 rows) staged to LDS with the esum normalization (and the
// ssum==0 -> 1 reference guard) applied at store time; register-prefetch of
// chunk c+1 overlaps compute. values rows are read as WAVE-UNIFORM s_loads
// (readfirstlane'd row) -> scalar pipe, no LDS broadcast cost; ctx reads are
// per-lane conflict-free b32.
// ---------------------------------------------------------------------------
__global__ __launch_bounds__(256) void k_out(
    const float* __restrict__ values, const float* __restrict__ csum,
    const float* __restrict__ esum,   float* __restrict__ out)
{
    const int tid  = threadIdx.x;
    const int lane = tid & 63;
    const int wave = tid >> 6;
    int r0 = blockIdx.x * 8 + wave * 2;          // wave's first row
    r0 = __builtin_amdgcn_readfirstlane(r0);     // force scalar addressing

    __shared__ float ctx_l[100 * 64];            // 25.6 KB

    float4 cbuf[7];                              // ctx chunk: 1600 float4 / 256 thr
    float  ebuf[7];                              // matching esum values

    float acc0 = 0.0f, acc1 = 0.0f;

    // ---- prefetch chunk 0 (lane-coalesced) ----
    {
        const float4* cp = (const float4*)csum;  // k0 = 0
        #pragma unroll
        for (int q = 0; q < 7; ++q) {
            const int t = tid + q * 256;
            if (t < 1600) { cbuf[q] = cp[t]; ebuf[q] = esum[t >> 4]; }
        }
    }

    for (int chunk = 0; chunk < 5; ++chunk) {
        __syncthreads();                         // LDS free (prev compute done)
        // ---- registers -> LDS with normalization ----
        {
            float4* cl = (float4*)ctx_l;
            #pragma unroll
            for (int q = 0; q < 7; ++q) {
                const int t = tid + q * 256;
                if (t < 1600) {
                    const float e   = ebuf[q];
                    const float inv = (e == 0.0f) ? 1.0f : __builtin_amdgcn_rcpf(e);
                    float4 c = cbuf[q];
                    c.x *= inv; c.y *= inv; c.z *= inv; c.w *= inv;
                    cl[t] = c;
                }
            }
        }
        __syncthreads();

        // ---- issue prefetch of chunk+1 (loads fly during compute) ----
        if (chunk < 4) {
            const int k0n = (chunk + 1) * 100;
            const float4* cp = (const float4*)(csum + (size_t)k0n * 64);
            #pragma unroll
            for (int q = 0; q < 7; ++q) {
                const int t = tid + q * 256;
                if (t < 1600) { cbuf[q] = cp[t]; ebuf[q] = esum[k0n + (t >> 4)]; }
            }
        }

        // ---- compute current chunk: ctx from LDS, values via s_loads ----
        const int k0 = chunk * 100;
        const float* v0 = values + (size_t)(r0 + 0) * 500 + k0;  // scalar ptr
        const float* v1 = values + (size_t)(r0 + 1) * 500 + k0;
        #pragma unroll 10
        for (int k = 0; k < 100; k += 4) {
            const float c0 = ctx_l[(k + 0) * 64 + lane];
            const float c1 = ctx_l[(k + 1) * 64 + lane];
            const float c2 = ctx_l[(k + 2) * 64 + lane];
            const float c3 = ctx_l[(k + 3) * 64 + lane];
            acc0 = fmaf(v0[k + 0], c0, acc0); acc0 = fmaf(v0[k + 1], c1, acc0);
            acc0 = fmaf(v0[k + 2], c2, acc0); acc0 = fmaf(v0[k + 3], c3, acc0);
            acc1 = fmaf(v1[k + 0], c0, acc1); acc1 = fmaf(v1[k + 1], c1, acc1);
            acc1 = fmaf(v1[k + 2], c2, acc1); acc1 = fmaf(v1[k + 3], c3, acc1);
        }
    }

    out[(size_t)(r0 + 0) * 64 + lane] = acc0;    // coalesced 256 B per wave
    out[(size_t)(r0 + 1) * 64 + lane] = acc1;
}

// ---------------------------------------------------------------------------
extern "C" void kernel_launch(void* const* d_in, const int* in_sizes, int n_in,
                              void* d_out, int out_size, void* d_ws, size_t ws_size,
                              hipStream_t stream)
{
    const float* values = (const float*)d_in[0];   // (4096, 500)
    const float* feat   = (const float*)d_in[1];   // (500, 64)
    const float* hid    = (const float*)d_in[2];   // (2000, 64)
    const float* Ww     = (const float*)d_in[3];   // (128, 64)
    const float* bw     = (const float*)d_in[4];   // (64,)
    const float* Wu     = (const float*)d_in[5];   // (64, 1)
    const void*  mask   = d_in[6];                 // (500, 2500, 1) — dtype detected on device
    float* out = (float*)d_out;                    // (4096, 64)

    // Workspace layout (floats):
    //   pre_f[32000] | pre_w[160000] | csum[32000] | esum[512]
    float* wsf   = (float*)d_ws;
    float* pre_f = wsf;                  // 32000 floats
    float* pre_w = wsf + 32000;          // 160000 floats (row-major 2500 x 64)
    float* csum  = wsf + 192000;         // 32000 floats (zeroed by k_pre)
    float* esum  = wsf + 224000;         // 512 floats   (zeroed by k_pre)

    k_pre <<<750,  256, 0, stream>>>(feat, hid, Ww, bw, pre_f, pre_w, csum);
    k_attn<<<1000, 256, 0, stream>>>(feat, hid, pre_f, pre_w, Wu, mask, csum, esum);
    k_out <<<512,  256, 0, stream>>>(values, csum, esum, out);
}